// Round 9
// baseline (16138.251 us; speedup 1.0000x reference)
//
#include <hip/hip_runtime.h>
#include <hip/hip_bf16.h>
#include <stdint.h>

// Decoder: 2-layer LSTM, B=2048, T=96, H=1024, teacher forcing=1.0.
// Round 9: register-resident W. Block = 256 batch x 64 gates, 8 waves =
// 2(kg K-split) x 2(ng 32-gate) x 2(mg 128-batch). Per wave: W-slice
// (32 n' x K/2) held in 256/136 VGPRs, filled once per block from a
// frag-layout W_fill buffer. Only A streams through LDS (32KB, 2-way swizzle).
// kg partial gates merged via LDS exchange; kg0 waves do fused cell + proj.
// D_t = {L2(t) || L1(t+1)}, grid 1024, 2 blocks/CU resident.

#define BB  2048
#define TT  96
#define NG  4096

typedef __bf16 bf16;
typedef __bf16 bf16x8 __attribute__((ext_vector_type(8)));
typedef float  f32x4  __attribute__((ext_vector_type(4)));

__device__ __forceinline__ float sigm(float x) { return 1.0f / (1.0f + __expf(-x)); }

__device__ __forceinline__ void gload16(const bf16* g, bf16* l) {
  __builtin_amdgcn_global_load_lds((const __attribute__((address_space(1))) void*)g,
                                   (__attribute__((address_space(3))) void*)l, 16, 0, 0);
}

#define SB() __builtin_amdgcn_sched_barrier(0)

// ---------------- prep kernels ----------------
// Gate-interleaved n' = h*4 + gate. W_fill layout (per MFMA fragment):
// [tnb][kg][ng][f][lane][j]: n' = tnb*64 + ng*32 + (f&1)*16 + (lane&15),
// k = kg*KHALF + (f>>1)*32 + (lane>>4)*8 + j.
// L2 (KHALF=1024, F=64): A = [h1 | h2]; k<1024 -> Wih1, else Whh1.
// L1 (KHALF=544,  F=34): A = [h1 | x];  k<1024 -> Whh0, else Wih0 (60) / pad.

__global__ __launch_bounds__(256) void build_wf1(const float* __restrict__ Wih1,
                                                 const float* __restrict__ Whh1,
                                                 bf16* __restrict__ Wf) {
  int idx = blockIdx.x * 256 + threadIdx.x;            // 2^23 total
  if (idx >= 64 * 2 * 2 * 64 * 512) return;
  int j = idx & 7, lane = (idx >> 3) & 63, f = (idx >> 9) & 63;
  int ng = (idx >> 15) & 1, kg = (idx >> 16) & 1, tnb = idx >> 17;
  int np = tnb * 64 + ng * 32 + (f & 1) * 16 + (lane & 15);
  int k  = kg * 1024 + (f >> 1) * 32 + (lane >> 4) * 8 + j;
  int n  = (np & 3) * 1024 + (np >> 2);
  float v = (k < 1024) ? Wih1[n * 1024 + k] : Whh1[n * 1024 + (k - 1024)];
  Wf[idx] = (bf16)v;
}

__global__ __launch_bounds__(256) void build_wf0(const float* __restrict__ Wih0,
                                                 const float* __restrict__ Whh0,
                                                 bf16* __restrict__ Wf) {
  int idx = blockIdx.x * 256 + threadIdx.x;            // 64*2*2*34*512
  if (idx >= 64 * 2 * 2 * 34 * 512) return;
  int j = idx & 7, lane = (idx >> 3) & 63;
  int f = (idx >> 9) % 34, rest = (idx >> 9) / 34;
  int ng = rest & 1, kg = (rest >> 1) & 1, tnb = rest >> 2;
  int np = tnb * 64 + ng * 32 + (f & 1) * 16 + (lane & 15);
  int k  = kg * 544 + (f >> 1) * 32 + (lane >> 4) * 8 + j;
  int n  = (np & 3) * 1024 + (np >> 2);
  float v;
  if (k < 1024)            v = Whh0[n * 1024 + k];
  else if (k - 1024 < 60)  v = Wih0[n * 60 + (k - 1024)];
  else                     v = 0.0f;
  Wf[idx] = (bf16)v;
}

__global__ __launch_bounds__(256) void perm_bias(const float* __restrict__ b0,
                                                 const float* __restrict__ b1,
                                                 float* __restrict__ b0p,
                                                 float* __restrict__ b1p) {
  int idx = blockIdx.x * 256 + threadIdx.x;
  if (idx >= NG) return;
  int n = (idx & 3) * 1024 + (idx >> 2);
  b0p[idx] = b0[n];
  b1p[idx] = b1[n];
}

// X2 layout: [t][b][64]; features [prev_y, dec(32), cat(11), gemb(16), pad4]
__global__ __launch_bounds__(256) void build_x2(
    const float* __restrict__ dec, const float* __restrict__ ty, const float* __restrict__ lec,
    const int* __restrict__ gid, const int* __restrict__ cp, const int* __restrict__ cct,
    const int* __restrict__ cpt, const int* __restrict__ ccl,
    const float* __restrict__ gemb, const float* __restrict__ ep, const float* __restrict__ ect,
    const float* __restrict__ ept, const float* __restrict__ ecl,
    bf16* __restrict__ X2) {
  int idx = blockIdx.x * 256 + threadIdx.x;  // over T*B
  if (idx >= BB * TT) return;
  int t = idx >> 11, b = idx & 2047;
  bf16* x = X2 + (size_t)idx * 64;
  x[0] = (bf16)((t == 0) ? lec[b] : ty[b * TT + t - 1]);
  const float* d = dec + ((size_t)b * TT + t) * 32;
  #pragma unroll
  for (int k = 0; k < 32; ++k) x[1 + k] = (bf16)d[k];
  const float* e;
  e = ep  + cp[b]  * 4;  for (int j = 0; j < 4;  ++j) x[33 + j] = (bf16)e[j];
  e = ect + cct[b] * 2;  for (int j = 0; j < 2;  ++j) x[37 + j] = (bf16)e[j];
  e = ept + cpt[b] * 3;  for (int j = 0; j < 3;  ++j) x[39 + j] = (bf16)e[j];
  e = ecl + ccl[b] * 2;  for (int j = 0; j < 2;  ++j) x[42 + j] = (bf16)e[j];
  e = gemb + gid[b] * 16; for (int j = 0; j < 16; ++j) x[44 + j] = (bf16)e[j];
  for (int j = 60; j < 64; ++j) x[j] = (bf16)0.0f;
}

__global__ __launch_bounds__(256) void init_state(const float* __restrict__ enc_h,
                                                  const float* __restrict__ enc_c,
                                                  bf16* __restrict__ H1b,
                                                  bf16* __restrict__ H2b,
                                                  float* __restrict__ c1t,
                                                  float* __restrict__ c2t) {
  int idx = blockIdx.x * 256 + threadIdx.x;  // over B*H
  if (idx >= BB * 1024) return;
  int b = idx >> 10, h = idx & 1023;
  H1b[idx] = (bf16)enc_h[idx];
  H2b[idx] = (bf16)enc_h[(size_t)BB * 1024 + idx];
  c1t[(size_t)h * BB + b] = enc_c[idx];
  c2t[(size_t)h * BB + b] = enc_c[(size_t)BB * 1024 + idx];
}

// ---------------- register-W GEMM + fused cell ----------------
// gates(b,n') = A(b,:).W(n',:). mfma(wreg, afrag): lane f32x4 = {i,f,g,o}
// of cell (b = tm+mg*128+mf*16+l15, h = (tn>>2)+ng*8+nf*4+u).
// MODE 1: K=2048 [h1|h2], NT=32. MODE 0: K=1088 [h1|x], halves 544, NT=17.

template <int MODE>
__device__ __forceinline__ void body(
    int tnb, int tm, int t,
    const bf16* __restrict__ PA, const bf16* __restrict__ PB,
    const bf16* __restrict__ Wf, const float* __restrict__ bperm,
    float* __restrict__ ct, bf16* __restrict__ Hout,
    const float* __restrict__ wp, const float* __restrict__ bp,
    float* __restrict__ y, bf16* smem)
{
  constexpr int NT = MODE ? 32 : 17;
  constexpr int FR = MODE ? 64 : 34;
  const int tn = tnb * 64;

  const int tid = threadIdx.x;
  const int lane = tid & 63, w = tid >> 6;
  const int l15 = lane & 15, u = lane >> 4;
  const int kg = w >> 2, mg = (w >> 1) & 1, ng = w & 1;

  // ---- W fill: 256/136 VGPRs, compile-time indexed (rule #20) ----
  const bf16* wsrc = Wf + ((((size_t)tnb * 2 + kg) * 2 + ng) * FR) * 512 + lane * 8;
  bf16x8 wreg[FR];
  #pragma unroll
  for (int f = 0; f < FR; ++f)
    wreg[f] = *reinterpret_cast<const bf16x8*>(wsrc + (size_t)f * 512);

  f32x4 acc[16];
  #pragma unroll
  for (int i = 0; i < 16; ++i) acc[i] = (f32x4){0.f, 0.f, 0.f, 0.f};

  // ---- A staging (both kg tiles), 2-way swizzle both sides ----
  bf16* As = smem;                       // [2 kg][256 rows][32 k] = 32KB
  auto asrc = [&](int kgi, int row, int r) -> const bf16* {
    if constexpr (MODE == 1) {
      const bf16* base = kgi ? PB : PA;
      return base + (size_t)(tm + row) * 1024 + r * 32;
    } else {
      if (kgi == 0) return PA + (size_t)(tm + row) * 1024 + r * 32;
      int k = 544 + r * 32;
      if (k < 1024) return PA + (size_t)(tm + row) * 1024 + k;
      return PB + (size_t)(tm + row) * 64 + (k - 1024);
    }
  };
  auto stage = [&](int r) {
    #pragma unroll
    for (int kgi = 0; kgi < 2; ++kgi)
      #pragma unroll
      for (int half = 0; half < 2; ++half) {
        int s = half * 512 + tid;
        int row = s >> 2;
        int ks = (s & 3) ^ ((row >> 1) & 3);     // pre-swizzled source slot
        gload16(asrc(kgi, row, r) + ks * 8, As + kgi * 8192 + s * 8);
      }
  };

  const int klocal = ((u ^ (l15 >> 1)) & 3) << 3;  // swizzled read offset

  stage(0);
  __syncthreads();

  #pragma unroll
  for (int r = 0; r < NT; ++r) {
    bf16x8 af[8];
    #pragma unroll
    for (int mf = 0; mf < 8; ++mf)
      af[mf] = *reinterpret_cast<const bf16x8*>(
          As + kg * 8192 + (mg * 128 + mf * 16 + l15) * 32 + klocal);
    __syncthreads();                 // all reads done -> buffer free
    if (r + 1 < NT) stage(r + 1);
    SB();
    __builtin_amdgcn_s_setprio(1);
    #pragma unroll
    for (int mf = 0; mf < 8; ++mf)
      #pragma unroll
      for (int nf = 0; nf < 2; ++nf)
        acc[mf * 2 + nf] = __builtin_amdgcn_mfma_f32_16x16x32_bf16(
            wreg[r * 2 + nf], af[mf], acc[mf * 2 + nf], 0, 0, 0);
    __builtin_amdgcn_s_setprio(0);
    __syncthreads();                 // next tile landed (vmcnt drained)
  }

  // ---- kg merge via LDS (conflict-free: lane-stride f32) ----
  float* ex = (float*)smem;          // [4 (mg,ng)][16 f][4 j][64 lanes] = 64KB
  const int reg4 = (mg * 2 + ng) * 16;
  if (kg == 1) {
    #pragma unroll
    for (int f = 0; f < 16; ++f)
      #pragma unroll
      for (int j = 0; j < 4; ++j)
        ex[(reg4 + f) * 256 + j * 64 + lane] = acc[f][j];
  }
  __syncthreads();

  const int hq = (tn >> 2) + ng * 8;       // wave h base (8 h values)
  const int bgb = tm + mg * 128;           // wave batch base
  float yp[8] = {0.f, 0.f, 0.f, 0.f, 0.f, 0.f, 0.f, 0.f};
  float hn_v[16];

  if (kg == 0) {
    #pragma unroll
    for (int f = 0; f < 16; ++f) {
      int mf = f >> 1, nf = f & 1;
      int hg = hq + nf * 4 + u;
      int bg = bgb + mf * 16 + l15;
      f32x4 bv = *reinterpret_cast<const f32x4*>(&bperm[hg * 4]);
      float gi = acc[f][0] + ex[(reg4 + f) * 256 +   0 + lane] + bv[0];
      float gf = acc[f][1] + ex[(reg4 + f) * 256 +  64 + lane] + bv[1];
      float gg = acc[f][2] + ex[(reg4 + f) * 256 + 128 + lane] + bv[2];
      float go = acc[f][3] + ex[(reg4 + f) * 256 + 192 + lane] + bv[3];
      float* cp_ = ct + (size_t)hg * BB + bg;
      float c = *cp_;
      float cn = sigm(gf) * c + sigm(gi) * tanhf(gg);
      float hn = sigm(go) * tanhf(cn);
      *cp_ = cn;
      hn_v[f] = hn;
      if constexpr (MODE == 1) yp[mf] += hn * wp[hg];
    }
  }
  __syncthreads();                   // all ex reads done -> smem reusable

  if (kg == 0) {
    bf16* hst = smem + w * 1024;     // [128 rows][8 h] bf16 = 2KB per wave
    #pragma unroll
    for (int f = 0; f < 16; ++f) {
      int mf = f >> 1, nf = f & 1;
      hst[(mf * 16 + l15) * 8 + nf * 4 + u] = (bf16)hn_v[f];
    }
    asm volatile("s_waitcnt lgkmcnt(0)" ::: "memory");
    SB();
    #pragma unroll
    for (int q = 0; q < 2; ++q) {
      int row = lane * 2 + q;
      bf16x8 v = *reinterpret_cast<const bf16x8*>(&hst[row * 8]);
      *reinterpret_cast<bf16x8*>(&Hout[(size_t)(bgb + row) * 1024 + hq]) = v;
    }
    if constexpr (MODE == 1) {
      #pragma unroll
      for (int mf = 0; mf < 8; ++mf) {
        float s = yp[mf];
        s += __shfl_xor(s, 16);
        s += __shfl_xor(s, 32);
        if (lane < 16)
          atomicAdd(&y[(size_t)(bgb + mf * 16 + lane) * TT + t], s);
      }
    }
  }
  if constexpr (MODE == 0) {
    // init y[:, t] = b_proj before dispatch t's L2 atomics (tn==0 blocks)
    if (tnb == 0 && tid < 256) y[(size_t)(tm + tid) * TT + t] = bp[0];
  }
}

// Grid 1024: bids [0,512) = L2(t); [512,1024) = L1(t+1). all_l1: grid 512.
// Decode (XCD-grouped W panels): x=v&7, j=v>>3: tm=(j&7)*256, tnb=x*8+(j>>3).
__global__ __launch_bounds__(512) void step_kernel(
    const bf16* __restrict__ H1in, const bf16* __restrict__ H2in,
    bf16* __restrict__ H1out, bf16* __restrict__ H2out,
    const bf16* __restrict__ X2,
    const bf16* __restrict__ Wf0, const bf16* __restrict__ Wf1,
    const float* __restrict__ b0p, const float* __restrict__ b1p,
    float* __restrict__ c1t, float* __restrict__ c2t,
    const float* __restrict__ wp, const float* __restrict__ bp,
    float* __restrict__ y, int t2, int all_l1) {
  __shared__ alignas(16) bf16 smem[32768];   // 64KB
  int bid = (int)blockIdx.x;
  int mode, v;
  if (all_l1) { mode = 0; v = bid; }
  else        { mode = (bid < 512) ? 1 : 0; v = bid & 511; }
  int x = v & 7, j = v >> 3;
  int tm = (j & 7) << 8;
  int tnb = x * 8 + (j >> 3);
  if (mode == 0) {
    int t1 = t2 + 1;
    if (t1 >= TT) return;
    body<0>(tnb, tm, t1, H1in, X2 + (size_t)t1 * BB * 64,
            Wf0, b0p, c1t, H1out, nullptr, bp, y, smem);
  } else {
    body<1>(tnb, tm, t2, H1in, H2in,
            Wf1, b1p, c2t, H2out, wp, nullptr, y, smem);
  }
}

// ---------------- launch ----------------

extern "C" void kernel_launch(void* const* d_in, const int* in_sizes, int n_in,
                              void* d_out, int out_size, void* d_ws, size_t ws_size,
                              hipStream_t stream) {
  const float* dec   = (const float*)d_in[0];
  const float* ty    = (const float*)d_in[1];
  const float* enc_h = (const float*)d_in[2];
  const float* enc_c = (const float*)d_in[3];
  const float* lec   = (const float*)d_in[4];
  const int*   gid   = (const int*)d_in[5];
  const int*   cp    = (const int*)d_in[6];
  const int*   cct   = (const int*)d_in[7];
  const int*   cpt   = (const int*)d_in[8];
  const int*   ccl   = (const int*)d_in[9];
  const float* gemb  = (const float*)d_in[10];
  const float* ep    = (const float*)d_in[11];
  const float* ect   = (const float*)d_in[12];
  const float* ept   = (const float*)d_in[13];
  const float* ecl   = (const float*)d_in[14];
  const float* Wih0  = (const float*)d_in[15];
  const float* Whh0  = (const float*)d_in[16];
  const float* b0    = (const float*)d_in[17];
  const float* Wih1  = (const float*)d_in[18];
  const float* Whh1  = (const float*)d_in[19];
  const float* b1    = (const float*)d_in[20];
  const float* wp    = (const float*)d_in[21];
  const float* bp    = (const float*)d_in[22];
  float* y = (float*)d_out;

  char* ws = (char*)d_ws;
  bf16* Wf1   = (bf16*)ws;  ws += (size_t)64 * 2 * 2 * 64 * 512 * 2;  // 16.8 MB
  bf16* Wf0   = (bf16*)ws;  ws += (size_t)64 * 2 * 2 * 34 * 512 * 2;  //  8.9 MB
  bf16* X2    = (bf16*)ws;  ws += (size_t)BB * TT * 64 * 2;           // 25.2 MB
  bf16* H1a   = (bf16*)ws;  ws += (size_t)BB * 1024 * 2;              //  4.2 MB each
  bf16* H1b   = (bf16*)ws;  ws += (size_t)BB * 1024 * 2;
  bf16* H2a   = (bf16*)ws;  ws += (size_t)BB * 1024 * 2;
  bf16* H2b   = (bf16*)ws;  ws += (size_t)BB * 1024 * 2;
  float* c1t  = (float*)ws; ws += (size_t)BB * 1024 * 4;              //  8.4 MB
  float* c2t  = (float*)ws; ws += (size_t)BB * 1024 * 4;              //  8.4 MB
  float* b0p  = (float*)ws; ws += (size_t)NG * 4;
  float* b1p  = (float*)ws; ws += (size_t)NG * 4;

  build_wf1<<<(64 * 2 * 2 * 64 * 512) / 256, 256, 0, stream>>>(Wih1, Whh1, Wf1);
  build_wf0<<<(64 * 2 * 2 * 34 * 512) / 256, 256, 0, stream>>>(Wih0, Whh0, Wf0);
  perm_bias<<<NG / 256, 256, 0, stream>>>(b0, b1, b0p, b1p);
  build_x2<<<(BB * TT + 255) / 256, 256, 0, stream>>>(dec, ty, lec, gid, cp, cct, cpt, ccl,
                                                      gemb, ep, ect, ept, ecl, X2);
  init_state<<<(BB * 1024) / 256, 256, 0, stream>>>(enc_h, enc_c, H1b, H2b, c1t, c2t);

  // prologue: L1(0) alone (grid 512). h1(t) in H1[t even ? a : b] ping-pong.
  step_kernel<<<512, 512, 0, stream>>>(H1b, nullptr, H1a, nullptr, X2, Wf0, Wf1,
                                       b0p, b1p, c1t, c2t, wp, bp, y, -1, 1);
  for (int t = 0; t < TT; ++t) {
    bf16* h1i = (t & 1) ? H1b : H1a;
    bf16* h1o = (t & 1) ? H1a : H1b;
    bf16* h2i = (t & 1) ? H2a : H2b;
    bf16* h2o = (t & 1) ? H2b : H2a;
    step_kernel<<<1024, 512, 0, stream>>>(h1i, h2i, h1o, h2o, X2, Wf0, Wf1,
                                          b0p, b1p, c1t, c2t, wp, bp, y, t, 0);
  }
}

// Round 10
// 6879.668 us; speedup vs baseline: 2.3458x; 2.3458x over previous
//
#include <hip/hip_runtime.h>
#include <hip/hip_bf16.h>
#include <stdint.h>

// Decoder: 2-layer LSTM, B=2048, T=96, H=1024, teacher forcing=1.0.
// Round 10: 256x128 tiles, 8 waves of 64x64 (R3's per-wave work), BK=32,
// 48KB LDS dbuf, 2 blocks/CU (16 waves/CU, 4/SIMD = R3's TLP) with 28% less
// staged volume and 2x less W re-staging. Single barrier per K-iter.
// D_t = {L2(t) || L1(t+1)}, grid 512, XCD-stable tn panels.

#define BB  2048
#define TT  96
#define NG  4096
#define KL1 1088      // 64 (x pad) + 1024 (h1)
#define KL2 2048      // h1 | h2

typedef __bf16 bf16;
typedef __bf16 bf16x8 __attribute__((ext_vector_type(8)));
typedef float  f32x4  __attribute__((ext_vector_type(4)));

__device__ __forceinline__ float sigm(float x) { return 1.0f / (1.0f + __expf(-x)); }
__device__ __forceinline__ float ftanh(float x) { return 2.0f / (1.0f + __expf(-2.0f * x)) - 1.0f; }

__device__ __forceinline__ void gload16(const bf16* g, bf16* l) {
  __builtin_amdgcn_global_load_lds((const __attribute__((address_space(1))) void*)g,
                                   (__attribute__((address_space(3))) void*)l, 16, 0, 0);
}

#define SB() __builtin_amdgcn_sched_barrier(0)

// ---------------- prep kernels ----------------
// Weight rows permuted: out row n' = h*4 + gate  <-  in row gate*1024 + h.

__global__ __launch_bounds__(256) void build_w0(const float* __restrict__ Wih0,
                                                const float* __restrict__ Whh0,
                                                bf16* __restrict__ W0) {
  int idx = blockIdx.x * 256 + threadIdx.x;
  if (idx >= NG * KL1) return;
  int np = idx / KL1, k = idx % KL1;
  int n = (np & 3) * 1024 + (np >> 2);
  float v;
  if (k < 60)       v = Wih0[n * 60 + k];
  else if (k < 64)  v = 0.0f;
  else              v = Whh0[n * 1024 + (k - 64)];
  W0[idx] = (bf16)v;
}

__global__ __launch_bounds__(256) void build_w1(const float* __restrict__ Wih1,
                                                const float* __restrict__ Whh1,
                                                bf16* __restrict__ W1) {
  int idx = blockIdx.x * 256 + threadIdx.x;
  if (idx >= NG * KL2) return;
  int np = idx >> 11, k = idx & 2047;
  int n = (np & 3) * 1024 + (np >> 2);
  float v = (k < 1024) ? Wih1[n * 1024 + k] : Whh1[n * 1024 + (k - 1024)];
  W1[idx] = (bf16)v;
}

__global__ __launch_bounds__(256) void perm_bias(const float* __restrict__ b0,
                                                 const float* __restrict__ b1,
                                                 float* __restrict__ b0p,
                                                 float* __restrict__ b1p) {
  int idx = blockIdx.x * 256 + threadIdx.x;
  if (idx >= NG) return;
  int n = (idx & 3) * 1024 + (idx >> 2);
  b0p[idx] = b0[n];
  b1p[idx] = b1[n];
}

// X layout: [b][t][64]
__global__ __launch_bounds__(256) void build_x(
    const float* __restrict__ dec, const float* __restrict__ ty, const float* __restrict__ lec,
    const int* __restrict__ gid, const int* __restrict__ cp, const int* __restrict__ cct,
    const int* __restrict__ cpt, const int* __restrict__ ccl,
    const float* __restrict__ gemb, const float* __restrict__ ep, const float* __restrict__ ect,
    const float* __restrict__ ept, const float* __restrict__ ecl,
    bf16* __restrict__ X) {
  int idx = blockIdx.x * 256 + threadIdx.x;  // over B*T
  if (idx >= BB * TT) return;
  int b = idx / TT, t = idx % TT;
  bf16* x = X + (size_t)idx * 64;
  x[0] = (bf16)((t == 0) ? lec[b] : ty[b * TT + t - 1]);
  const float* d = dec + (size_t)idx * 32;
  #pragma unroll
  for (int k = 0; k < 32; ++k) x[1 + k] = (bf16)d[k];
  const float* e;
  e = ep  + cp[b]  * 4;  for (int j = 0; j < 4;  ++j) x[33 + j] = (bf16)e[j];
  e = ect + cct[b] * 2;  for (int j = 0; j < 2;  ++j) x[37 + j] = (bf16)e[j];
  e = ept + cpt[b] * 3;  for (int j = 0; j < 3;  ++j) x[39 + j] = (bf16)e[j];
  e = ecl + ccl[b] * 2;  for (int j = 0; j < 2;  ++j) x[42 + j] = (bf16)e[j];
  e = gemb + gid[b] * 16; for (int j = 0; j < 16; ++j) x[44 + j] = (bf16)e[j];
  for (int j = 60; j < 64; ++j) x[j] = (bf16)0.0f;
}

__global__ __launch_bounds__(256) void init_state(const float* __restrict__ enc_h,
                                                  const float* __restrict__ enc_c,
                                                  bf16* __restrict__ H1b,
                                                  bf16* __restrict__ H2b,
                                                  float* __restrict__ c1t,
                                                  float* __restrict__ c2t) {
  int idx = blockIdx.x * 256 + threadIdx.x;  // over B*H
  if (idx >= BB * 1024) return;
  int b = idx >> 10, h = idx & 1023;
  H1b[idx] = (bf16)enc_h[idx];
  H2b[idx] = (bf16)enc_h[(size_t)BB * 1024 + idx];
  c1t[(size_t)h * BB + b] = enc_c[idx];
  c2t[(size_t)h * BB + b] = enc_c[(size_t)BB * 1024 + idx];
}

// ---------------- fused GEMM + cell body (256 batch x 128 gates, 8 waves) ----
// gates(b, n') = A(b,:) . W(n',:), n' = h*4 + gate (gate-interleaved weights).
// mfma(W_frag, A_frag): lane's f32x4 = {i,f,g,o} of one (b,h) cell.
// Wave w: wb=w&3 (64-batch quadrant), wg=w>>2 (64-gate half). acc[4][4] = 64 AGPR.
// MODE 0: A = [x(t) | h1(t-1)], K=1088, writes h1(t).
// MODE 1: A = [h1(t) | h2(t-1)], K=2048, writes h2(t) + y(t).
// LDS swizzle: stored kslot s at row r = source kslot s ^ ((r>>1)&3). Both sides.

template <int MODE>
__device__ __forceinline__ void gemm_cell_body(
    int tm, int tn, int t,
    const bf16* __restrict__ P0, const bf16* __restrict__ P1,
    const bf16* __restrict__ Wt, const float* __restrict__ bperm,
    float* __restrict__ ct, bf16* __restrict__ Hout,
    const float* __restrict__ wp, const float* __restrict__ bp,
    float* __restrict__ y,
    bf16* As, bf16* Ws) {      // As [2][256*32], Ws [2][128*32]
  constexpr int KT = (MODE == 0) ? KL1 : KL2;
  constexpr int NT = KT / 32;

  int tid = threadIdx.x;
  int lane = tid & 63;
  int w = tid >> 6;
  int wb = (w & 3) << 6;      // batch quadrant base (0/64/128/192)
  int wg = (w >> 2) << 6;     // gate half base (0/64)

  f32x4 acc[4][4];
  #pragma unroll
  for (int mw = 0; mw < 4; ++mw)
    #pragma unroll
    for (int nb = 0; nb < 4; ++nb) acc[mw][nb] = (f32x4){0.f, 0.f, 0.f, 0.f};

  // staging: A slots sA0=tid, sA1=512+tid (1024 slots -> 256 rows x 4 kslots);
  //          W slot  sW=tid   (512 slots  -> 128 rows x 4 kslots).
  // source kslot = (s&3) ^ ((row>>1)&3)   [inverse of read swizzle]
  int rA0 = tid >> 2, rA1 = (512 + tid) >> 2, rW = tid >> 2;
  int kcA0 = (((tid & 3) ^ ((rA0 >> 1) & 3)) << 3);
  int kcA1 = (((tid & 3) ^ ((rA1 >> 1) & 3)) << 3);
  int kcW  = kcA0;
  int dA0 = (tid & ~63) * 8;
  int dA1 = 4096 + dA0;             // slots 512.. start at elem 4096
  int dW  = dA0;

  auto aptr = [&](int row, int gk) -> const bf16* {
    if constexpr (MODE == 0) {
      return (gk < 64) ? (P0 + ((size_t)(tm + row) * TT + t) * 64 + gk)
                       : (P1 + (size_t)(tm + row) * 1024 + (gk - 64));
    } else {
      return (gk < 1024) ? (P0 + (size_t)(tm + row) * 1024 + gk)
                         : (P1 + (size_t)(tm + row) * 1024 + (gk - 1024));
    }
  };
  auto stage = [&](int kt, int buf) {
    int gk0 = kt * 32 + kcA0, gk1 = kt * 32 + kcA1, gkw = kt * 32 + kcW;
    gload16(aptr(rA0, gk0), As + buf * 8192 + dA0);
    gload16(aptr(rA1, gk1), As + buf * 8192 + dA1);
    gload16(Wt + (size_t)(tn + rW) * KT + gkw, Ws + buf * 4096 + dW);
  };

  // prologue
  stage(0, 0);
  __syncthreads();

  int lrow = lane & 15;
  // read: logical kslot K = lane>>4 at row base+lrow -> stored K ^ ((lrow>>1)&3)
  int klocal = ((((lane >> 4) ^ (lrow >> 1)) & 3) << 3);

  for (int kt = 0; kt < NT; ++kt) {
    int buf = kt & 1;
    if (kt + 1 < NT) stage(kt + 1, buf ^ 1);
    SB();  // keep prefetch issue ahead of compute

    bf16x8 af[4], wf[4];
    #pragma unroll
    for (int nb = 0; nb < 4; ++nb)
      af[nb] = *reinterpret_cast<const bf16x8*>(&As[buf * 8192 + (wb + nb * 16 + lrow) * 32 + klocal]);
    #pragma unroll
    for (int mw = 0; mw < 4; ++mw)
      wf[mw] = *reinterpret_cast<const bf16x8*>(&Ws[buf * 4096 + (wg + mw * 16 + lrow) * 32 + klocal]);

    __builtin_amdgcn_s_setprio(1);
    #pragma unroll
    for (int mw = 0; mw < 4; ++mw)
      #pragma unroll
      for (int nb = 0; nb < 4; ++nb)
        acc[mw][nb] = __builtin_amdgcn_mfma_f32_16x16x32_bf16(wf[mw], af[nb], acc[mw][nb], 0, 0, 0);
    __builtin_amdgcn_s_setprio(0);

    __syncthreads();  // drains prefetch vmcnt; next buffer ready; reads done
  }

  // ---- fused cell epilogue (hst reuses As buf0; all K-loop reads fenced) ----
  bf16* hst = As + w * 1024;          // 64 b x 16 h per wave (8 KB total)
  int u = lane >> 4;                  // h sub-index
  int bl = lane & 15;                 // batch sub-index
  int hwave = (tn + wg) >> 2;         // wave's global h base (16 h values)
  int bgb = tm + wb;                  // wave's batch base (64 rows)
  float yp[4] = {0.f, 0.f, 0.f, 0.f};

  #pragma unroll
  for (int mw = 0; mw < 4; ++mw) {
    int hg = hwave + mw * 4 + u;
    f32x4 bv = *reinterpret_cast<const f32x4*>(&bperm[hg * 4]);
    float wph = 0.f;
    if constexpr (MODE == 1) wph = wp[hg];
    #pragma unroll
    for (int nb = 0; nb < 4; ++nb) {
      int bg = bgb + nb * 16 + bl;
      float gi = acc[mw][nb][0] + bv[0];
      float gf = acc[mw][nb][1] + bv[1];
      float gg = acc[mw][nb][2] + bv[2];
      float go = acc[mw][nb][3] + bv[3];
      float* cp_ = ct + (size_t)hg * BB + bg;
      float c = *cp_;
      float cn = sigm(gf) * c + sigm(gi) * ftanh(gg);
      float hn = sigm(go) * ftanh(cn);
      *cp_ = cn;
      hst[(nb * 16 + bl) * 16 + mw * 4 + u] = (bf16)hn;
      if constexpr (MODE == 1) yp[nb] += hn * wph;
    }
  }

  asm volatile("s_waitcnt lgkmcnt(0)" ::: "memory");
  SB();

  // coalesced Hout write-out: wave patch = 64 batch x 16 h
  #pragma unroll
  for (int q = 0; q < 2; ++q) {
    int chunk = q * 64 + lane;
    int row = chunk >> 1, half = chunk & 1;
    bf16x8 v = *reinterpret_cast<const bf16x8*>(&hst[row * 16 + half * 8]);
    *reinterpret_cast<bf16x8*>(&Hout[(size_t)(bgb + row) * 1024 + hwave + half * 8]) = v;
  }

  if constexpr (MODE == 1) {
    #pragma unroll
    for (int nb = 0; nb < 4; ++nb) {
      float s = yp[nb];
      s += __shfl_xor(s, 16);
      s += __shfl_xor(s, 32);
      if (lane < 16)
        atomicAdd(&y[(size_t)(bgb + nb * 16 + lane) * TT + t], s);
    }
  } else {
    // init y[:, t] = b_proj before dispatch t's L2 atomics (tn==0 blocks)
    if (tn == 0 && tid < 256) y[(size_t)(tm + tid) * TT + t] = bp[0];
  }
}

// Grid 512: bids [0,256) = L2(t); [256,512) = L1(t+1). all_l1: grid 256.
// Decode (XCD-stable W panels): v=bid&255; x=v&7; j=v>>3:
//   tm = (j&7)*256, tn = (x*4 + (j>>3))*128.
__global__ __launch_bounds__(512, 4) void step_kernel(
    const bf16* __restrict__ H1in, const bf16* __restrict__ H2in,
    bf16* __restrict__ H1out, bf16* __restrict__ H2out,
    const bf16* __restrict__ X,
    const bf16* __restrict__ W0, const bf16* __restrict__ W1,
    const float* __restrict__ b0p, const float* __restrict__ b1p,
    float* __restrict__ c1t, float* __restrict__ c2t,
    const float* __restrict__ wp, const float* __restrict__ bp,
    float* __restrict__ y, int t2, int only_l1) {
  __shared__ alignas(16) bf16 As[2 * 8192];   // 32 KB
  __shared__ alignas(16) bf16 Ws[2 * 4096];   // 16 KB
  int bid = (int)blockIdx.x;
  int v = bid & 255;
  int x = v & 7, j = v >> 3;
  int tm = (j & 7) << 8;
  int tn = ((x << 2) + (j >> 3)) << 7;
  if (only_l1 || bid >= 256) {
    int t1 = t2 + 1;
    if (t1 >= TT) return;
    gemm_cell_body<0>(tm, tn, t1, X, H1in, W0, b0p, c1t, H1out, nullptr, bp, y, As, Ws);
  } else {
    gemm_cell_body<1>(tm, tn, t2, H1in, H2in, W1, b1p, c2t, H2out, wp, nullptr, y, As, Ws);
  }
}

// ---------------- launch ----------------

extern "C" void kernel_launch(void* const* d_in, const int* in_sizes, int n_in,
                              void* d_out, int out_size, void* d_ws, size_t ws_size,
                              hipStream_t stream) {
  const float* dec   = (const float*)d_in[0];
  const float* ty    = (const float*)d_in[1];
  const float* enc_h = (const float*)d_in[2];
  const float* enc_c = (const float*)d_in[3];
  const float* lec   = (const float*)d_in[4];
  const int*   gid   = (const int*)d_in[5];
  const int*   cp    = (const int*)d_in[6];
  const int*   cct   = (const int*)d_in[7];
  const int*   cpt   = (const int*)d_in[8];
  const int*   ccl   = (const int*)d_in[9];
  const float* gemb  = (const float*)d_in[10];
  const float* ep    = (const float*)d_in[11];
  const float* ect   = (const float*)d_in[12];
  const float* ept   = (const float*)d_in[13];
  const float* ecl   = (const float*)d_in[14];
  const float* Wih0  = (const float*)d_in[15];
  const float* Whh0  = (const float*)d_in[16];
  const float* b0    = (const float*)d_in[17];
  const float* Wih1  = (const float*)d_in[18];
  const float* Whh1  = (const float*)d_in[19];
  const float* b1    = (const float*)d_in[20];
  const float* wp    = (const float*)d_in[21];
  const float* bp    = (const float*)d_in[22];
  float* y = (float*)d_out;

  char* ws = (char*)d_ws;
  bf16* W0    = (bf16*)ws;  ws += (size_t)NG * KL1 * 2;      //  8.9 MB
  bf16* W1    = (bf16*)ws;  ws += (size_t)NG * KL2 * 2;      // 16.8 MB
  bf16* X     = (bf16*)ws;  ws += (size_t)BB * TT * 64 * 2;  // 25.2 MB
  bf16* H1a   = (bf16*)ws;  ws += (size_t)BB * 1024 * 2;     //  4.2 MB each
  bf16* H1b   = (bf16*)ws;  ws += (size_t)BB * 1024 * 2;
  bf16* H2a   = (bf16*)ws;  ws += (size_t)BB * 1024 * 2;
  bf16* H2b   = (bf16*)ws;  ws += (size_t)BB * 1024 * 2;
  float* c1t  = (float*)ws; ws += (size_t)BB * 1024 * 4;     //  8.4 MB
  float* c2t  = (float*)ws; ws += (size_t)BB * 1024 * 4;     //  8.4 MB
  float* b0p  = (float*)ws; ws += (size_t)NG * 4;
  float* b1p  = (float*)ws; ws += (size_t)NG * 4;

  build_w0<<<(NG * KL1 + 255) / 256, 256, 0, stream>>>(Wih0, Whh0, W0);
  build_w1<<<(NG * KL2 + 255) / 256, 256, 0, stream>>>(Wih1, Whh1, W1);
  perm_bias<<<NG / 256, 256, 0, stream>>>(b0, b1, b0p, b1p);
  build_x<<<(BB * TT + 255) / 256, 256, 0, stream>>>(dec, ty, lec, gid, cp, cct, cpt, ccl,
                                                     gemb, ep, ect, ept, ecl, X);
  init_state<<<(BB * 1024) / 256, 256, 0, stream>>>(enc_h, enc_c, H1b, H2b, c1t, c2t);

  // prologue: L1(0) alone (grid 256). h1(t) in H1[t&1]; h2(t) in H2[t&1].
  step_kernel<<<256, 512, 0, stream>>>(H1b, nullptr, H1a, nullptr, X, W0, W1,
                                       b0p, b1p, c1t, c2t, wp, bp, y, -1, 1);
  for (int t = 0; t < TT; ++t) {
    bf16* h1i = (t & 1) ? H1b : H1a;
    bf16* h1o = (t & 1) ? H1a : H1b;
    bf16* h2i = (t & 1) ? H2a : H2b;
    bf16* h2o = (t & 1) ? H2b : H2a;
    step_kernel<<<512, 512, 0, stream>>>(h1i, h2i, h1o, h2o, X, W0, W1,
                                         b0p, b1p, c1t, c2t, wp, bp, y, t, 0);
  }
}